// Round 1
// baseline (2749.005 us; speedup 1.0000x reference)
//
#include <hip/hip_runtime.h>

static constexpr int N_USERS = 1000000;
static constexpr int N_ITEMS = 200000;
static constexpr int N_EDGES = 25000000;

// ---------------------------------------------------------------------------
// Kernel A: init sums in workspace.
//   sumw1[u] = exp(w0[u])   (self term)
//   sumw2[i] = 0
// Must run every call: d_ws is not re-poisoned between replays, and we
// accumulate into it.
// ---------------------------------------------------------------------------
__global__ __launch_bounds__(256) void k_init(const float* __restrict__ w0,
                                              float* __restrict__ sumw1,
                                              float* __restrict__ sumw2) {
    int tid = blockIdx.x * blockDim.x + threadIdx.x;
    int stride = gridDim.x * blockDim.x;
    for (int u = tid; u < N_USERS; u += stride) sumw1[u] = __expf(w0[u]);
    for (int i = tid; i < N_ITEMS; i += stride) sumw2[i] = 0.0f;
}

// ---------------------------------------------------------------------------
// Kernel B: scatter-accumulate exp(w1) into sumw1[r1], exp(w2) into sumw2[r2].
// float4/int4 loads for coalescing; atomics are random-address by nature.
// ---------------------------------------------------------------------------
__global__ __launch_bounds__(256) void k_accum(const float4* __restrict__ w1,
                                               const float4* __restrict__ w2,
                                               const int4* __restrict__ r1,
                                               const int4* __restrict__ r2,
                                               float* __restrict__ sumw1,
                                               float* __restrict__ sumw2) {
    const int nv = N_EDGES / 4;
    int tid = blockIdx.x * blockDim.x + threadIdx.x;
    int stride = gridDim.x * blockDim.x;
    for (int v = tid; v < nv; v += stride) {
        float4 a = w1[v];
        int4 u = r1[v];
        atomicAdd(&sumw1[u.x], __expf(a.x));
        atomicAdd(&sumw1[u.y], __expf(a.y));
        atomicAdd(&sumw1[u.z], __expf(a.z));
        atomicAdd(&sumw1[u.w], __expf(a.w));
        float4 b = w2[v];
        int4 it = r2[v];
        atomicAdd(&sumw2[it.x], __expf(b.x));
        atomicAdd(&sumw2[it.y], __expf(b.y));
        atomicAdd(&sumw2[it.z], __expf(b.z));
        atomicAdd(&sumw2[it.w], __expf(b.w));
    }
}

// ---------------------------------------------------------------------------
// Kernel C: per-edge finalize. Re-reads w1/w2 (recompute exp — cheaper than
// storing expw in HBM), gathers L2-resident sums, writes lfw1/lfw2.
// ---------------------------------------------------------------------------
__global__ __launch_bounds__(256) void k_edges(const float4* __restrict__ w1,
                                               const float4* __restrict__ w2,
                                               const int4* __restrict__ r1,
                                               const int4* __restrict__ r2,
                                               const float* __restrict__ sumw1,
                                               const float* __restrict__ sumw2,
                                               float4* __restrict__ lfw1,
                                               float4* __restrict__ lfw2) {
    const int nv = N_EDGES / 4;
    int tid = blockIdx.x * blockDim.x + threadIdx.x;
    int stride = gridDim.x * blockDim.x;
    for (int v = tid; v < nv; v += stride) {
        float4 a = w1[v];
        int4 u = r1[v];
        float4 o1;
        o1.x = __expf(a.x) / sumw1[u.x];
        o1.y = __expf(a.y) / sumw1[u.y];
        o1.z = __expf(a.z) / sumw1[u.z];
        o1.w = __expf(a.w) / sumw1[u.w];
        lfw1[v] = o1;
        float4 b = w2[v];
        int4 it = r2[v];
        float4 o2;
        o2.x = __expf(b.x) / sumw2[it.x];
        o2.y = __expf(b.y) / sumw2[it.y];
        o2.z = __expf(b.z) / sumw2[it.z];
        o2.w = __expf(b.w) / sumw2[it.w];
        lfw2[v] = o2;
    }
}

// ---------------------------------------------------------------------------
// Kernel D: per-user finalize. lfw0[u] = exp(w0[u]) / sumw1[u].
// ---------------------------------------------------------------------------
__global__ __launch_bounds__(256) void k_users(const float4* __restrict__ w0,
                                               const float4* __restrict__ sumw1,
                                               float4* __restrict__ lfw0) {
    const int nv = N_USERS / 4;
    int tid = blockIdx.x * blockDim.x + threadIdx.x;
    int stride = gridDim.x * blockDim.x;
    for (int v = tid; v < nv; v += stride) {
        float4 a = w0[v];
        float4 s = sumw1[v];
        float4 o;
        o.x = __expf(a.x) / s.x;
        o.y = __expf(a.y) / s.y;
        o.z = __expf(a.z) / s.z;
        o.w = __expf(a.w) / s.w;
        lfw0[v] = o;
    }
}

extern "C" void kernel_launch(void* const* d_in, const int* in_sizes, int n_in,
                              void* d_out, int out_size, void* d_ws, size_t ws_size,
                              hipStream_t stream) {
    const float* w0 = (const float*)d_in[0];
    const float* w1 = (const float*)d_in[1];
    const float* w2 = (const float*)d_in[2];
    const int* r1 = (const int*)d_in[3];
    const int* r2 = (const int*)d_in[4];

    float* out = (float*)d_out;
    float* lfw0 = out;                       // [N_USERS]
    float* lfw1 = out + N_USERS;             // [N_EDGES]
    float* lfw2 = out + N_USERS + N_EDGES;   // [N_EDGES]

    float* sumw1 = (float*)d_ws;             // [N_USERS]
    float* sumw2 = sumw1 + N_USERS;          // [N_ITEMS]

    // A: init sums (every call — ws holds stale sums from previous replay)
    k_init<<<1024, 256, 0, stream>>>(w0, sumw1, sumw2);

    // B: scatter-accumulate
    k_accum<<<2048, 256, 0, stream>>>((const float4*)w1, (const float4*)w2,
                                      (const int4*)r1, (const int4*)r2,
                                      sumw1, sumw2);

    // C: edge finalize
    k_edges<<<2048, 256, 0, stream>>>((const float4*)w1, (const float4*)w2,
                                      (const int4*)r1, (const int4*)r2,
                                      sumw1, sumw2,
                                      (float4*)lfw1, (float4*)lfw2);

    // D: user finalize
    k_users<<<1024, 256, 0, stream>>>((const float4*)w0, (const float4*)sumw1,
                                      (float4*)lfw0);
}

// Round 2
// 2718.896 us; speedup vs baseline: 1.0111x; 1.0111x over previous
//
#include <hip/hip_runtime.h>

static constexpr int N_USERS = 1000000;
static constexpr int N_ITEMS = 200000;
static constexpr int N_EDGES = 25000000;
static constexpr int NC = 8;   // one bin-array copy per XCD

typedef float f4 __attribute__((ext_vector_type(4)));
typedef int   i4 __attribute__((ext_vector_type(4)));

// Physical XCD id of this wave's CU (m09: HW_REG_XCC_ID verified on gfx950).
__device__ __forceinline__ int xcc_id() {
    int x;
    asm volatile("s_getreg_b32 %0, hwreg(HW_REG_XCC_ID, 0, 4)" : "=s"(x));
    return x & (NC - 1);
}

template<bool WG>
__device__ __forceinline__ void atadd(float* p, float v) {
    if constexpr (WG) {
        // Workgroup scope -> no device-coherence bit -> cached RMW in the
        // local XCD L2 (no 32B HBM write-through per atomic). Correct only
        // because each XCD owns a private copy of the bin array.
        __hip_atomic_fetch_add(p, v, __ATOMIC_RELAXED, __HIP_MEMORY_SCOPE_WORKGROUP);
    } else {
        atomicAdd(p, v);
    }
}

// ---------------------------------------------------------------------------
// Zero the privatized copies (every call: ws persists across graph replays).
// ---------------------------------------------------------------------------
__global__ __launch_bounds__(256) void k_zero(f4* __restrict__ p, int n4) {
    int tid = blockIdx.x * blockDim.x + threadIdx.x;
    int stride = gridDim.x * blockDim.x;
    f4 z = {0.f, 0.f, 0.f, 0.f};
    for (int v = tid; v < n4; v += stride) p[v] = z;
}

// ---------------------------------------------------------------------------
// Scatter-accumulate exp(w) into copies[xcd][r]. Streaming loads are
// non-temporal so they don't evict the L2-resident bin copy.
// ---------------------------------------------------------------------------
template<bool WG>
__global__ __launch_bounds__(256) void k_accum(const f4* __restrict__ w,
                                               const i4* __restrict__ r,
                                               float* __restrict__ copies,
                                               int bins) {
    float* mine = copies + (WG ? (size_t)xcc_id() * bins : (size_t)0);
    const int nv = N_EDGES / 4;
    int tid = blockIdx.x * blockDim.x + threadIdx.x;
    int stride = gridDim.x * blockDim.x;
    for (int v = tid; v < nv; v += stride) {
        f4 a = __builtin_nontemporal_load(&w[v]);
        i4 u = __builtin_nontemporal_load(&r[v]);
        atadd<WG>(&mine[u.x], __expf(a.x));
        atadd<WG>(&mine[u.y], __expf(a.y));
        atadd<WG>(&mine[u.z], __expf(a.z));
        atadd<WG>(&mine[u.w], __expf(a.w));
    }
}

// ---------------------------------------------------------------------------
// Reduce the NC copies into finals; emit lfw0 for free.
//   finals1[u] = exp(w0[u]) + sum_c copies1[c][u];  lfw0[u] = exp(w0[u])/finals1[u]
//   finals2[i] = sum_c copies2[c][i]
// (nc==1 aliased case: copies==finals, read-before-write per element is safe.)
// ---------------------------------------------------------------------------
__global__ __launch_bounds__(256) void k_reduce(const float* __restrict__ w0,
                                                const float* __restrict__ copies1,
                                                const float* __restrict__ copies2,
                                                float* __restrict__ finals1,
                                                float* __restrict__ finals2,
                                                float* __restrict__ lfw0,
                                                int nc) {
    int tid = blockIdx.x * blockDim.x + threadIdx.x;
    int stride = gridDim.x * blockDim.x;
    for (int u = tid; u < N_USERS; u += stride) {
        float e = __expf(w0[u]);
        float s = e;
        for (int c = 0; c < nc; ++c) s += copies1[(size_t)c * N_USERS + u];
        finals1[u] = s;
        lfw0[u] = e / s;
    }
    for (int i = tid; i < N_ITEMS; i += stride) {
        float s = 0.f;
        for (int c = 0; c < nc; ++c) s += copies2[(size_t)c * N_ITEMS + i];
        finals2[i] = s;
    }
}

// ---------------------------------------------------------------------------
// Per-edge finalize: lfw1 = exp(w1)/finals1[r1], lfw2 = exp(w2)/finals2[r2].
// Streaming in/out non-temporal; gathers (L3-resident finals) cached.
// ---------------------------------------------------------------------------
__global__ __launch_bounds__(256) void k_edges(const f4* __restrict__ w1,
                                               const f4* __restrict__ w2,
                                               const i4* __restrict__ r1,
                                               const i4* __restrict__ r2,
                                               const float* __restrict__ finals1,
                                               const float* __restrict__ finals2,
                                               f4* __restrict__ lfw1,
                                               f4* __restrict__ lfw2) {
    const int nv = N_EDGES / 4;
    int tid = blockIdx.x * blockDim.x + threadIdx.x;
    int stride = gridDim.x * blockDim.x;
    for (int v = tid; v < nv; v += stride) {
        f4 a = __builtin_nontemporal_load(&w1[v]);
        i4 u = __builtin_nontemporal_load(&r1[v]);
        f4 o1;
        o1.x = __expf(a.x) / finals1[u.x];
        o1.y = __expf(a.y) / finals1[u.y];
        o1.z = __expf(a.z) / finals1[u.z];
        o1.w = __expf(a.w) / finals1[u.w];
        __builtin_nontemporal_store(o1, &lfw1[v]);
        f4 b = __builtin_nontemporal_load(&w2[v]);
        i4 it = __builtin_nontemporal_load(&r2[v]);
        f4 o2;
        o2.x = __expf(b.x) / finals2[it.x];
        o2.y = __expf(b.y) / finals2[it.y];
        o2.z = __expf(b.z) / finals2[it.z];
        o2.w = __expf(b.w) / finals2[it.w];
        __builtin_nontemporal_store(o2, &lfw2[v]);
    }
}

extern "C" void kernel_launch(void* const* d_in, const int* in_sizes, int n_in,
                              void* d_out, int out_size, void* d_ws, size_t ws_size,
                              hipStream_t stream) {
    const float* w0 = (const float*)d_in[0];
    const float* w1 = (const float*)d_in[1];
    const float* w2 = (const float*)d_in[2];
    const int* r1 = (const int*)d_in[3];
    const int* r2 = (const int*)d_in[4];

    float* out = (float*)d_out;
    float* lfw0 = out;                       // [N_USERS]
    float* lfw1 = out + N_USERS;             // [N_EDGES]
    float* lfw2 = out + N_USERS + N_EDGES;   // [N_EDGES]

    float* ws = (float*)d_ws;
    float* finals1 = ws;                     // [N_USERS]
    float* finals2 = ws + N_USERS;           // [N_ITEMS]

    size_t need = (size_t)(N_USERS + N_ITEMS) * (NC + 1) * sizeof(float);
    bool priv = ws_size >= need;

    float* copies1 = priv ? ws + (N_USERS + N_ITEMS) : finals1;       // [nc][N_USERS]
    float* copies2 = priv ? copies1 + (size_t)NC * N_USERS : finals2; // [nc][N_ITEMS]
    int nc = priv ? NC : 1;
    int zero4 = nc * (N_USERS + N_ITEMS) / 4;   // copies1/copies2 contiguous

    k_zero<<<2048, 256, 0, stream>>>((f4*)copies1, zero4);

    if (priv) {
        k_accum<true><<<2048, 256, 0, stream>>>((const f4*)w1, (const i4*)r1,
                                                copies1, N_USERS);
        k_accum<true><<<2048, 256, 0, stream>>>((const f4*)w2, (const i4*)r2,
                                                copies2, N_ITEMS);
    } else {
        k_accum<false><<<2048, 256, 0, stream>>>((const f4*)w1, (const i4*)r1,
                                                 copies1, N_USERS);
        k_accum<false><<<2048, 256, 0, stream>>>((const f4*)w2, (const i4*)r2,
                                                 copies2, N_ITEMS);
    }

    k_reduce<<<2048, 256, 0, stream>>>(w0, copies1, copies2,
                                       finals1, finals2, lfw0, nc);

    k_edges<<<2048, 256, 0, stream>>>((const f4*)w1, (const f4*)w2,
                                      (const i4*)r1, (const i4*)r2,
                                      finals1, finals2,
                                      (f4*)lfw1, (f4*)lfw2);
}

// Round 3
// 1256.054 us; speedup vs baseline: 2.1886x; 2.1646x over previous
//
#include <hip/hip_runtime.h>
#include <stdint.h>

static constexpr int N_USERS = 1000000;
static constexpr int N_ITEMS = 200000;
static constexpr int N_EDGES = 25000000;

// Partition geometry: NBLK blocks each own a contiguous CHUNK of edges.
static constexpr int NBLK  = 512;
static constexpr int CHUNK = 48832;              // NBLK*CHUNK = 25,001,984 >= N_EDGES, %4==0
static constexpr int SHIFT_U = 10;               // users: 1024 bins per bucket
static constexpr int SHIFT_I = 8;                // items:  256 bins per bucket
static constexpr int NB_U = (N_USERS + (1 << SHIFT_U) - 1) >> SHIFT_U;  // 977 buckets
static constexpr int NB_I = (N_ITEMS + (1 << SHIFT_I) - 1) >> SHIFT_I;  // 782 buckets

typedef float f4 __attribute__((ext_vector_type(4)));
typedef int   i4 __attribute__((ext_vector_type(4)));

// ---------------------------------------------------------------------------
// P1: per-block bucket partition. Block blk owns edges [blk*CHUNK, min(...,E)).
//   pass i : LDS histogram of bucket = idx >> SHIFT
//   scan   : LDS exclusive scan -> per-(block,bucket) start offsets
//   pass ii: scatter packed payload into the block's own contiguous region,
//            grouped by bucket. payload = (bits(exp(w)) & 0xFFFFF000) | lidx.
// No global atomics anywhere. All global writes are block-private.
// ---------------------------------------------------------------------------
template<int SHIFT, int NB>
__global__ __launch_bounds__(1024) void k_part(const float* __restrict__ w,
                                               const int* __restrict__ r,
                                               uint32_t* __restrict__ payload,
                                               uint32_t* __restrict__ starts,   // [NBLK][NB]
                                               uint32_t* __restrict__ counts) { // [NBLK][NB]
    __shared__ uint32_t hist[1024];     // histogram, then absolute write cursors
    __shared__ uint32_t scanbuf[1024];
    const int blk = blockIdx.x;
    const int t = threadIdx.x;
    const uint32_t base = (uint32_t)blk * CHUNK;
    const int begin = blk * CHUNK;
    const int end = (begin + CHUNK < N_EDGES) ? begin + CHUNK : N_EDGES;
    const int nv = (end - begin) >> 2;           // always divisible by 4

    hist[t] = 0;
    __syncthreads();

    const i4* r4 = (const i4*)(r + begin);
    const f4* w4 = (const f4*)(w + begin);

    // pass i: histogram
    for (int v = t; v < nv; v += 1024) {
        i4 u = __builtin_nontemporal_load(&r4[v]);
        atomicAdd(&hist[(uint32_t)u.x >> SHIFT], 1u);
        atomicAdd(&hist[(uint32_t)u.y >> SHIFT], 1u);
        atomicAdd(&hist[(uint32_t)u.z >> SHIFT], 1u);
        atomicAdd(&hist[(uint32_t)u.w >> SHIFT], 1u);
    }
    __syncthreads();

    // exclusive scan over 1024 entries (entries >= NB are zero)
    uint32_t c = hist[t];
    scanbuf[t] = c;
    __syncthreads();
    for (int d = 1; d < 1024; d <<= 1) {
        uint32_t y = (t >= d) ? scanbuf[t - d] : 0u;
        __syncthreads();
        scanbuf[t] += y;
        __syncthreads();
    }
    uint32_t excl = scanbuf[t] - c;

    if (t < NB) {
        starts[blk * NB + t] = base + excl;
        counts[blk * NB + t] = c;
    }
    hist[t] = base + excl;                       // absolute cursor
    __syncthreads();

    // pass ii: scatter (grouped by bucket within the block's region)
    const uint32_t lmask = (1u << SHIFT) - 1u;
    for (int v = t; v < nv; v += 1024) {
        i4 u = __builtin_nontemporal_load(&r4[v]);
        f4 a = __builtin_nontemporal_load(&w4[v]);
        {
            uint32_t idx = (uint32_t)u.x;
            uint32_t pos = atomicAdd(&hist[idx >> SHIFT], 1u);
            payload[pos] = (__float_as_uint(__expf(a.x)) & 0xFFFFF000u) | (idx & lmask);
        }
        {
            uint32_t idx = (uint32_t)u.y;
            uint32_t pos = atomicAdd(&hist[idx >> SHIFT], 1u);
            payload[pos] = (__float_as_uint(__expf(a.y)) & 0xFFFFF000u) | (idx & lmask);
        }
        {
            uint32_t idx = (uint32_t)u.z;
            uint32_t pos = atomicAdd(&hist[idx >> SHIFT], 1u);
            payload[pos] = (__float_as_uint(__expf(a.z)) & 0xFFFFF000u) | (idx & lmask);
        }
        {
            uint32_t idx = (uint32_t)u.w;
            uint32_t pos = atomicAdd(&hist[idx >> SHIFT], 1u);
            payload[pos] = (__float_as_uint(__expf(a.w)) & 0xFFFFF000u) | (idx & lmask);
        }
    }
}

// ---------------------------------------------------------------------------
// P2: one block per bucket. Gather the bucket's runs from all NBLK regions,
// accumulate into LDS bins with LDS float atomics, write finals.
// Users variant fuses the exp(w0) self term and emits lfw0.
// ---------------------------------------------------------------------------
template<int SHIFT, int NB>
__global__ __launch_bounds__(1024) void k_bucket(const uint32_t* __restrict__ payload,
                                                 const uint32_t* __restrict__ starts,
                                                 const uint32_t* __restrict__ counts,
                                                 int nelems,
                                                 const float* __restrict__ w0,   // null for items
                                                 float* __restrict__ finals,
                                                 float* __restrict__ lfw0) {     // null for items
    constexpr int BINS = 1 << SHIFT;
    __shared__ float bins[BINS];
    const int b = blockIdx.x;
    const int t = threadIdx.x;
    for (int i = t; i < BINS; i += 1024) bins[i] = 0.f;
    __syncthreads();

    const int wave = t >> 6, lane = t & 63;      // 16 waves
    for (int blk = wave; blk < NBLK; blk += 16) {
        uint32_t s = starts[blk * NB + b];
        uint32_t c = counts[blk * NB + b];
        for (uint32_t j = lane; j < c; j += 64) {
            uint32_t p = __builtin_nontemporal_load(&payload[s + j]);
            atomicAdd(&bins[p & (BINS - 1)], __uint_as_float(p & 0xFFFFF000u));
        }
    }
    __syncthreads();

    for (int i = t; i < BINS; i += 1024) {
        int g = b * BINS + i;
        if (g < nelems) {
            float s = bins[i];
            if (w0) {
                float e = __expf(w0[g]);
                s += e;
                finals[g] = s;
                lfw0[g] = e / s;
            } else {
                finals[g] = s;
            }
        }
    }
}

// ---------------------------------------------------------------------------
// Per-edge finalize: lfw1 = exp(w1)/finals1[r1], lfw2 = exp(w2)/finals2[r2].
// ---------------------------------------------------------------------------
__global__ __launch_bounds__(256) void k_edges(const f4* __restrict__ w1,
                                               const f4* __restrict__ w2,
                                               const i4* __restrict__ r1,
                                               const i4* __restrict__ r2,
                                               const float* __restrict__ finals1,
                                               const float* __restrict__ finals2,
                                               f4* __restrict__ lfw1,
                                               f4* __restrict__ lfw2) {
    const int nv = N_EDGES / 4;
    int tid = blockIdx.x * blockDim.x + threadIdx.x;
    int stride = gridDim.x * blockDim.x;
    for (int v = tid; v < nv; v += stride) {
        f4 a = __builtin_nontemporal_load(&w1[v]);
        i4 u = __builtin_nontemporal_load(&r1[v]);
        f4 o1;
        o1.x = __expf(a.x) / finals1[u.x];
        o1.y = __expf(a.y) / finals1[u.y];
        o1.z = __expf(a.z) / finals1[u.z];
        o1.w = __expf(a.w) / finals1[u.w];
        __builtin_nontemporal_store(o1, &lfw1[v]);
        f4 b = __builtin_nontemporal_load(&w2[v]);
        i4 it = __builtin_nontemporal_load(&r2[v]);
        f4 o2;
        o2.x = __expf(b.x) / finals2[it.x];
        o2.y = __expf(b.y) / finals2[it.y];
        o2.z = __expf(b.z) / finals2[it.z];
        o2.w = __expf(b.w) / finals2[it.w];
        __builtin_nontemporal_store(o2, &lfw2[v]);
    }
}

extern "C" void kernel_launch(void* const* d_in, const int* in_sizes, int n_in,
                              void* d_out, int out_size, void* d_ws, size_t ws_size,
                              hipStream_t stream) {
    const float* w0 = (const float*)d_in[0];
    const float* w1 = (const float*)d_in[1];
    const float* w2 = (const float*)d_in[2];
    const int* r1 = (const int*)d_in[3];
    const int* r2 = (const int*)d_in[4];

    float* out = (float*)d_out;
    float* lfw0 = out;                        // [N_USERS]
    float* lfw1 = out + N_USERS;              // [N_EDGES]
    float* lfw2 = out + N_USERS + N_EDGES;    // [N_EDGES]

    // Scratch payload (100 MB) lives in the lfw1/lfw2 region (200 MB): it is
    // fully consumed by k_bucket before k_edges overwrites the region.
    uint32_t* payload = (uint32_t*)(out + N_USERS);

    float* ws = (float*)d_ws;
    float* finals1 = ws;                      // [N_USERS]
    float* finals2 = ws + N_USERS;            // [N_ITEMS]
    uint32_t* starts = (uint32_t*)(ws + N_USERS + N_ITEMS);     // [NBLK*NB_U]
    uint32_t* counts = starts + (size_t)NBLK * NB_U;            // [NBLK*NB_U]

    // Relation 1 (users)
    k_part<SHIFT_U, NB_U><<<NBLK, 1024, 0, stream>>>(w1, r1, payload, starts, counts);
    k_bucket<SHIFT_U, NB_U><<<NB_U, 1024, 0, stream>>>(payload, starts, counts,
                                                       N_USERS, w0, finals1, lfw0);

    // Relation 2 (items) — reuses payload/starts/counts
    k_part<SHIFT_I, NB_I><<<NBLK, 1024, 0, stream>>>(w2, r2, payload, starts, counts);
    k_bucket<SHIFT_I, NB_I><<<NB_I, 1024, 0, stream>>>(payload, starts, counts,
                                                       N_ITEMS, nullptr, finals2, nullptr);

    // Per-edge finalize
    k_edges<<<2048, 256, 0, stream>>>((const f4*)w1, (const f4*)w2,
                                      (const i4*)r1, (const i4*)r2,
                                      finals1, finals2,
                                      (f4*)lfw1, (f4*)lfw2);
}

// Round 4
// 809.745 us; speedup vs baseline: 3.3949x; 1.5512x over previous
//
#include <hip/hip_runtime.h>
#include <stdint.h>

static constexpr int N_USERS = 1000000;
static constexpr int N_ITEMS = 200000;
static constexpr int N_EDGES = 25000000;

// Tile/partition geometry
static constexpr int TILE   = 16384;                 // edges per LDS-sorted tile
static constexpr int NTILES = 3;
static constexpr int CHUNK  = TILE * NTILES;         // 49152 edges per block
static constexpr int NBLK   = (N_EDGES + CHUNK - 1) / CHUNK;   // 509
static constexpr int RUNS   = NBLK * NTILES;         // runs per bucket = 1527

static constexpr int SHIFT_U = 10;                   // users: 1024 bins/bucket
static constexpr int SHIFT_I = 8;                    // items:  256 bins/bucket
static constexpr int NB_U = (N_USERS + (1 << SHIFT_U) - 1) >> SHIFT_U;  // 977
static constexpr int NB_I = (N_ITEMS + (1 << SHIFT_I) - 1) >> SHIFT_I;  // 782

typedef float    f4 __attribute__((ext_vector_type(4)));
typedef int      i4 __attribute__((ext_vector_type(4)));
typedef uint32_t u4 __attribute__((ext_vector_type(4)));

// ---------------------------------------------------------------------------
// P1: per-block tile-sorted partition. For each 16K-edge tile:
//   1) load r into regs, LDS histogram of bucket = idx >> SHIFT
//   2) two-level shfl scan (2 barriers)
//   3) scatter packed payload into LDS stage (no global write amplification)
//   4) coalesced u4 dump of the stage to global payload
// Metadata: starts[(blk*NTILES+tile)*(NB+1) + b], sentinel at b==NB.
// payload = (bits(exp(w)) & ~lmask) | (idx & lmask).
// ---------------------------------------------------------------------------
template<int SHIFT, int NB>
__global__ __launch_bounds__(1024) void k_part(const float* __restrict__ w,
                                               const int* __restrict__ r,
                                               uint32_t* __restrict__ payload,
                                               uint32_t* __restrict__ starts) {
    __shared__ uint32_t stage[TILE];     // 64 KB
    __shared__ uint32_t hist[1024];      // histogram, then write cursors
    __shared__ uint32_t wsum[16];
    const int blk = blockIdx.x;
    const int t = threadIdx.x;
    const int lane = t & 63, wave = t >> 6;
    const int begin = blk * CHUNK;
    const int bend = (begin + CHUNK < N_EDGES) ? begin + CHUNK : N_EDGES;
    const uint32_t lmask = (1u << SHIFT) - 1u;

    for (int tile = 0; tile < NTILES; ++tile) {
        const int tb = begin + tile * TILE;
        int n = bend - tb;
        n = n < 0 ? 0 : (n > TILE ? TILE : n);
        const int n4 = n >> 2;                       // all boundaries %4 == 0
        const size_t mbase = (size_t)(blk * NTILES + tile) * (NB + 1);

        hist[t] = 0;
        __syncthreads();

        // 1) load indices (kept in registers) + histogram
        uint32_t idx[16];
        #pragma unroll
        for (int k = 0; k < 4; ++k) {
            int v = t + k * 1024;
            if (v < n4) {
                i4 u = __builtin_nontemporal_load((const i4*)r + (tb >> 2) + v);
                idx[4 * k + 0] = (uint32_t)u.x;
                idx[4 * k + 1] = (uint32_t)u.y;
                idx[4 * k + 2] = (uint32_t)u.z;
                idx[4 * k + 3] = (uint32_t)u.w;
                atomicAdd(&hist[(uint32_t)u.x >> SHIFT], 1u);
                atomicAdd(&hist[(uint32_t)u.y >> SHIFT], 1u);
                atomicAdd(&hist[(uint32_t)u.z >> SHIFT], 1u);
                atomicAdd(&hist[(uint32_t)u.w >> SHIFT], 1u);
            }
        }
        __syncthreads();

        // 2) exclusive scan of hist[0..1023]: wave shfl-scan + wave-total scan
        uint32_t c = hist[t];
        uint32_t x = c;
        #pragma unroll
        for (int d = 1; d < 64; d <<= 1) {
            uint32_t y = __shfl_up(x, d);
            if (lane >= d) x += y;
        }
        if (lane == 63) wsum[wave] = x;
        __syncthreads();
        if (t < 16) {
            uint32_t y = wsum[t];
            uint32_t s = y;
            #pragma unroll
            for (int d = 1; d < 16; d <<= 1) {
                uint32_t z = __shfl_up(s, d, 16);
                if (t >= d) s += z;
            }
            wsum[t] = s - y;                         // exclusive wave prefix
        }
        __syncthreads();
        uint32_t excl = x - c + wsum[wave];

        if (t < NB) starts[mbase + t] = (uint32_t)tb + excl;
        if (t == 0) starts[mbase + NB] = (uint32_t)(tb + n);  // sentinel
        hist[t] = excl;                              // tile-local cursors
        __syncthreads();

        // 3) scatter into LDS stage
        #pragma unroll
        for (int k = 0; k < 4; ++k) {
            int v = t + k * 1024;
            if (v < n4) {
                f4 a = __builtin_nontemporal_load((const f4*)w + (tb >> 2) + v);
                uint32_t p0 = atomicAdd(&hist[idx[4 * k + 0] >> SHIFT], 1u);
                stage[p0] = (__float_as_uint(__expf(a.x)) & ~lmask) | (idx[4 * k + 0] & lmask);
                uint32_t p1 = atomicAdd(&hist[idx[4 * k + 1] >> SHIFT], 1u);
                stage[p1] = (__float_as_uint(__expf(a.y)) & ~lmask) | (idx[4 * k + 1] & lmask);
                uint32_t p2 = atomicAdd(&hist[idx[4 * k + 2] >> SHIFT], 1u);
                stage[p2] = (__float_as_uint(__expf(a.z)) & ~lmask) | (idx[4 * k + 2] & lmask);
                uint32_t p3 = atomicAdd(&hist[idx[4 * k + 3] >> SHIFT], 1u);
                stage[p3] = (__float_as_uint(__expf(a.w)) & ~lmask) | (idx[4 * k + 3] & lmask);
            }
        }
        __syncthreads();

        // 4) coalesced dump of the sorted tile
        #pragma unroll
        for (int k = 0; k < 4; ++k) {
            int v = t + k * 1024;
            if (v < n4) {
                u4 s4 = ((const u4*)stage)[v];
                __builtin_nontemporal_store(s4, (u4*)payload + (tb >> 2) + v);
            }
        }
        __syncthreads();                             // before next tile's hist[]=0
    }
}

// ---------------------------------------------------------------------------
// P2: one block per bucket. Gather the bucket's RUNS runs (contiguous, ~17
// entries each), accumulate into LDS bins, write finals (+ fused lfw0 for
// the users relation).
// ---------------------------------------------------------------------------
template<int SHIFT, int NB>
__global__ __launch_bounds__(1024) void k_bucket(const uint32_t* __restrict__ payload,
                                                 const uint32_t* __restrict__ starts,
                                                 int nelems,
                                                 const float* __restrict__ w0,   // null for items
                                                 float* __restrict__ finals,
                                                 float* __restrict__ lfw0) {     // null for items
    constexpr int BINS = 1 << SHIFT;
    __shared__ float bins[BINS];
    const int b = blockIdx.x;
    const int t = threadIdx.x;
    const uint32_t lmask = (1u << SHIFT) - 1u;
    for (int i = t; i < BINS; i += 1024) bins[i] = 0.f;
    __syncthreads();

    const int wave = t >> 6, lane = t & 63;          // 16 waves
    for (int run = wave; run < RUNS; run += 16) {
        uint32_t s = starts[(size_t)run * (NB + 1) + b];
        uint32_t e = starts[(size_t)run * (NB + 1) + b + 1];
        for (uint32_t j = s + lane; j < e; j += 64) {
            uint32_t p = __builtin_nontemporal_load(&payload[j]);
            atomicAdd(&bins[p & lmask], __uint_as_float(p & ~lmask));
        }
    }
    __syncthreads();

    for (int i = t; i < BINS; i += 1024) {
        int g = b * BINS + i;
        if (g < nelems) {
            float s = bins[i];
            if (w0) {
                float e = __expf(w0[g]);
                s += e;
                finals[g] = s;
                lfw0[g] = e / s;
            } else {
                finals[g] = s;
            }
        }
    }
}

// ---------------------------------------------------------------------------
// Per-edge finalize: lfw1 = exp(w1)/finals1[r1], lfw2 = exp(w2)/finals2[r2].
// ---------------------------------------------------------------------------
__global__ __launch_bounds__(256) void k_edges(const f4* __restrict__ w1,
                                               const f4* __restrict__ w2,
                                               const i4* __restrict__ r1,
                                               const i4* __restrict__ r2,
                                               const float* __restrict__ finals1,
                                               const float* __restrict__ finals2,
                                               f4* __restrict__ lfw1,
                                               f4* __restrict__ lfw2) {
    const int nv = N_EDGES / 4;
    int tid = blockIdx.x * blockDim.x + threadIdx.x;
    int stride = gridDim.x * blockDim.x;
    for (int v = tid; v < nv; v += stride) {
        f4 a = __builtin_nontemporal_load(&w1[v]);
        i4 u = __builtin_nontemporal_load(&r1[v]);
        f4 o1;
        o1.x = __expf(a.x) / finals1[u.x];
        o1.y = __expf(a.y) / finals1[u.y];
        o1.z = __expf(a.z) / finals1[u.z];
        o1.w = __expf(a.w) / finals1[u.w];
        __builtin_nontemporal_store(o1, &lfw1[v]);
        f4 b = __builtin_nontemporal_load(&w2[v]);
        i4 it = __builtin_nontemporal_load(&r2[v]);
        f4 o2;
        o2.x = __expf(b.x) / finals2[it.x];
        o2.y = __expf(b.y) / finals2[it.y];
        o2.z = __expf(b.z) / finals2[it.z];
        o2.w = __expf(b.w) / finals2[it.w];
        __builtin_nontemporal_store(o2, &lfw2[v]);
    }
}

extern "C" void kernel_launch(void* const* d_in, const int* in_sizes, int n_in,
                              void* d_out, int out_size, void* d_ws, size_t ws_size,
                              hipStream_t stream) {
    const float* w0 = (const float*)d_in[0];
    const float* w1 = (const float*)d_in[1];
    const float* w2 = (const float*)d_in[2];
    const int* r1 = (const int*)d_in[3];
    const int* r2 = (const int*)d_in[4];

    float* out = (float*)d_out;
    float* lfw0 = out;                        // [N_USERS]
    float* lfw1 = out + N_USERS;              // [N_EDGES]
    float* lfw2 = out + N_USERS + N_EDGES;    // [N_EDGES]

    // Scratch payload (100 MB) lives in the lfw1/lfw2 region (200 MB): it is
    // fully consumed by k_bucket before k_edges overwrites the region.
    uint32_t* payload = (uint32_t*)(out + N_USERS);

    float* ws = (float*)d_ws;
    float* finals1 = ws;                      // [N_USERS]
    float* finals2 = ws + N_USERS;            // [N_ITEMS]
    uint32_t* starts = (uint32_t*)(ws + N_USERS + N_ITEMS);  // [RUNS*(NB_U+1)] max ~6MB

    // Relation 1 (users)
    k_part<SHIFT_U, NB_U><<<NBLK, 1024, 0, stream>>>(w1, r1, payload, starts);
    k_bucket<SHIFT_U, NB_U><<<NB_U, 1024, 0, stream>>>(payload, starts,
                                                       N_USERS, w0, finals1, lfw0);

    // Relation 2 (items) — reuses payload/starts
    k_part<SHIFT_I, NB_I><<<NBLK, 1024, 0, stream>>>(w2, r2, payload, starts);
    k_bucket<SHIFT_I, NB_I><<<NB_I, 1024, 0, stream>>>(payload, starts,
                                                       N_ITEMS, nullptr, finals2, nullptr);

    // Per-edge finalize
    k_edges<<<2048, 256, 0, stream>>>((const f4*)w1, (const f4*)w2,
                                      (const i4*)r1, (const i4*)r2,
                                      finals1, finals2,
                                      (f4*)lfw1, (f4*)lfw2);
}

// Round 5
// 759.504 us; speedup vs baseline: 3.6195x; 1.0661x over previous
//
#include <hip/hip_runtime.h>
#include <hip/hip_fp16.h>
#include <stdint.h>

static constexpr int N_USERS = 1000000;
static constexpr int N_ITEMS = 200000;
static constexpr int N_EDGES = 25000000;

// Tile/partition geometry
static constexpr int TILE   = 16384;                 // edges per LDS-sorted tile
static constexpr int NTILES = 3;
static constexpr int CHUNK  = TILE * NTILES;         // 49152 edges per block
static constexpr int NBLK   = (N_EDGES + CHUNK - 1) / CHUNK;   // 509
static constexpr int RUNS   = NBLK * NTILES;         // runs per bucket = 1527

static constexpr int SHIFT_U = 10;                   // users: 1024 bins/bucket
static constexpr int SHIFT_I = 8;                    // items:  256 bins/bucket
static constexpr int NB_U = (N_USERS + (1 << SHIFT_U) - 1) >> SHIFT_U;  // 977
static constexpr int NB_I = (N_ITEMS + (1 << SHIFT_I) - 1) >> SHIFT_I;  // 782

typedef float    f4 __attribute__((ext_vector_type(4)));
typedef int      i4 __attribute__((ext_vector_type(4)));
typedef uint32_t u4 __attribute__((ext_vector_type(4)));

// ---------------------------------------------------------------------------
// P1: per-block tile-sorted partition (unchanged from round 4).
// ---------------------------------------------------------------------------
template<int SHIFT, int NB>
__global__ __launch_bounds__(1024) void k_part(const float* __restrict__ w,
                                               const int* __restrict__ r,
                                               uint32_t* __restrict__ payload,
                                               uint32_t* __restrict__ starts) {
    __shared__ uint32_t stage[TILE];     // 64 KB
    __shared__ uint32_t hist[1024];      // histogram, then write cursors
    __shared__ uint32_t wsum[16];
    const int blk = blockIdx.x;
    const int t = threadIdx.x;
    const int lane = t & 63, wave = t >> 6;
    const int begin = blk * CHUNK;
    const int bend = (begin + CHUNK < N_EDGES) ? begin + CHUNK : N_EDGES;
    const uint32_t lmask = (1u << SHIFT) - 1u;

    for (int tile = 0; tile < NTILES; ++tile) {
        const int tb = begin + tile * TILE;
        int n = bend - tb;
        n = n < 0 ? 0 : (n > TILE ? TILE : n);
        const int n4 = n >> 2;                       // all boundaries %4 == 0
        const size_t mbase = (size_t)(blk * NTILES + tile) * (NB + 1);

        hist[t] = 0;
        __syncthreads();

        // 1) load indices (kept in registers) + histogram
        uint32_t idx[16];
        #pragma unroll
        for (int k = 0; k < 4; ++k) {
            int v = t + k * 1024;
            if (v < n4) {
                i4 u = __builtin_nontemporal_load((const i4*)r + (tb >> 2) + v);
                idx[4 * k + 0] = (uint32_t)u.x;
                idx[4 * k + 1] = (uint32_t)u.y;
                idx[4 * k + 2] = (uint32_t)u.z;
                idx[4 * k + 3] = (uint32_t)u.w;
                atomicAdd(&hist[(uint32_t)u.x >> SHIFT], 1u);
                atomicAdd(&hist[(uint32_t)u.y >> SHIFT], 1u);
                atomicAdd(&hist[(uint32_t)u.z >> SHIFT], 1u);
                atomicAdd(&hist[(uint32_t)u.w >> SHIFT], 1u);
            }
        }
        __syncthreads();

        // 2) exclusive scan of hist[0..1023]: wave shfl-scan + wave-total scan
        uint32_t c = hist[t];
        uint32_t x = c;
        #pragma unroll
        for (int d = 1; d < 64; d <<= 1) {
            uint32_t y = __shfl_up(x, d);
            if (lane >= d) x += y;
        }
        if (lane == 63) wsum[wave] = x;
        __syncthreads();
        if (t < 16) {
            uint32_t y = wsum[t];
            uint32_t s = y;
            #pragma unroll
            for (int d = 1; d < 16; d <<= 1) {
                uint32_t z = __shfl_up(s, d, 16);
                if (t >= d) s += z;
            }
            wsum[t] = s - y;                         // exclusive wave prefix
        }
        __syncthreads();
        uint32_t excl = x - c + wsum[wave];

        if (t < NB) starts[mbase + t] = (uint32_t)tb + excl;
        if (t == 0) starts[mbase + NB] = (uint32_t)(tb + n);  // sentinel
        hist[t] = excl;                              // tile-local cursors
        __syncthreads();

        // 3) scatter into LDS stage
        #pragma unroll
        for (int k = 0; k < 4; ++k) {
            int v = t + k * 1024;
            if (v < n4) {
                f4 a = __builtin_nontemporal_load((const f4*)w + (tb >> 2) + v);
                uint32_t p0 = atomicAdd(&hist[idx[4 * k + 0] >> SHIFT], 1u);
                stage[p0] = (__float_as_uint(__expf(a.x)) & ~lmask) | (idx[4 * k + 0] & lmask);
                uint32_t p1 = atomicAdd(&hist[idx[4 * k + 1] >> SHIFT], 1u);
                stage[p1] = (__float_as_uint(__expf(a.y)) & ~lmask) | (idx[4 * k + 1] & lmask);
                uint32_t p2 = atomicAdd(&hist[idx[4 * k + 2] >> SHIFT], 1u);
                stage[p2] = (__float_as_uint(__expf(a.z)) & ~lmask) | (idx[4 * k + 2] & lmask);
                uint32_t p3 = atomicAdd(&hist[idx[4 * k + 3] >> SHIFT], 1u);
                stage[p3] = (__float_as_uint(__expf(a.w)) & ~lmask) | (idx[4 * k + 3] & lmask);
            }
        }
        __syncthreads();

        // 4) coalesced dump of the sorted tile
        #pragma unroll
        for (int k = 0; k < 4; ++k) {
            int v = t + k * 1024;
            if (v < n4) {
                u4 s4 = ((const u4*)stage)[v];
                __builtin_nontemporal_store(s4, (u4*)payload + (tb >> 2) + v);
            }
        }
        __syncthreads();                             // before next tile's hist[]=0
    }
}

// ---------------------------------------------------------------------------
// P2: one block per bucket. Accumulate into LDS bins; emit f16 RECIPROCALS
// (2.4 MB total -> L2-resident for the gather in k_edges). Users variant
// fuses the exp(w0) self term and emits lfw0.
// ---------------------------------------------------------------------------
template<int SHIFT, int NB>
__global__ __launch_bounds__(1024) void k_bucket(const uint32_t* __restrict__ payload,
                                                 const uint32_t* __restrict__ starts,
                                                 int nelems,
                                                 const float* __restrict__ w0,   // null for items
                                                 __half* __restrict__ recip,
                                                 float* __restrict__ lfw0) {     // null for items
    constexpr int BINS = 1 << SHIFT;
    __shared__ float bins[BINS];
    const int b = blockIdx.x;
    const int t = threadIdx.x;
    const uint32_t lmask = (1u << SHIFT) - 1u;
    for (int i = t; i < BINS; i += 1024) bins[i] = 0.f;
    __syncthreads();

    const int wave = t >> 6, lane = t & 63;          // 16 waves
    for (int run = wave; run < RUNS; run += 16) {
        uint32_t s = starts[(size_t)run * (NB + 1) + b];
        uint32_t e = starts[(size_t)run * (NB + 1) + b + 1];
        for (uint32_t j = s + lane; j < e; j += 64) {
            uint32_t p = __builtin_nontemporal_load(&payload[j]);
            atomicAdd(&bins[p & lmask], __uint_as_float(p & ~lmask));
        }
    }
    __syncthreads();

    for (int i = t; i < BINS; i += 1024) {
        int g = b * BINS + i;
        if (g < nelems) {
            float s = bins[i];
            if (w0) {
                float e = __expf(w0[g]);
                s += e;
                lfw0[g] = e / s;
            }
            recip[g] = __float2half(1.0f / s);
        }
    }
}

// ---------------------------------------------------------------------------
// Per-edge finalize, unrolled x2 for MLP: 16 independent f16 gathers in
// flight per thread-iteration; gather tables (2.4 MB) are L2-resident.
//   lfw1 = exp(w1) * recip1[r1];  lfw2 = exp(w2) * recip2[r2]
// ---------------------------------------------------------------------------
__global__ __launch_bounds__(256) void k_edges(const f4* __restrict__ w1,
                                               const f4* __restrict__ w2,
                                               const i4* __restrict__ r1,
                                               const i4* __restrict__ r2,
                                               const __half* __restrict__ recip1,
                                               const __half* __restrict__ recip2,
                                               f4* __restrict__ lfw1,
                                               f4* __restrict__ lfw2) {
    const int nv2 = N_EDGES / 8;                     // 3,125,000 (exact)
    int tid = blockIdx.x * blockDim.x + threadIdx.x;
    int stride = gridDim.x * blockDim.x;
    for (int v2 = tid; v2 < nv2; v2 += stride) {
        int v = v2 * 2;
        // users relation, 8 edges
        i4 u0 = __builtin_nontemporal_load(&r1[v]);
        i4 u1 = __builtin_nontemporal_load(&r1[v + 1]);
        f4 a0 = __builtin_nontemporal_load(&w1[v]);
        f4 a1 = __builtin_nontemporal_load(&w1[v + 1]);
        float g0 = __half2float(recip1[u0.x]);
        float g1 = __half2float(recip1[u0.y]);
        float g2 = __half2float(recip1[u0.z]);
        float g3 = __half2float(recip1[u0.w]);
        float g4 = __half2float(recip1[u1.x]);
        float g5 = __half2float(recip1[u1.y]);
        float g6 = __half2float(recip1[u1.z]);
        float g7 = __half2float(recip1[u1.w]);
        // items relation, 8 edges
        i4 it0 = __builtin_nontemporal_load(&r2[v]);
        i4 it1 = __builtin_nontemporal_load(&r2[v + 1]);
        f4 b0 = __builtin_nontemporal_load(&w2[v]);
        f4 b1 = __builtin_nontemporal_load(&w2[v + 1]);
        float h0 = __half2float(recip2[it0.x]);
        float h1 = __half2float(recip2[it0.y]);
        float h2 = __half2float(recip2[it0.z]);
        float h3 = __half2float(recip2[it0.w]);
        float h4 = __half2float(recip2[it1.x]);
        float h5 = __half2float(recip2[it1.y]);
        float h6 = __half2float(recip2[it1.z]);
        float h7 = __half2float(recip2[it1.w]);

        f4 o0, o1;
        o0.x = __expf(a0.x) * g0;
        o0.y = __expf(a0.y) * g1;
        o0.z = __expf(a0.z) * g2;
        o0.w = __expf(a0.w) * g3;
        o1.x = __expf(a1.x) * g4;
        o1.y = __expf(a1.y) * g5;
        o1.z = __expf(a1.z) * g6;
        o1.w = __expf(a1.w) * g7;
        __builtin_nontemporal_store(o0, &lfw1[v]);
        __builtin_nontemporal_store(o1, &lfw1[v + 1]);

        f4 p0, p1;
        p0.x = __expf(b0.x) * h0;
        p0.y = __expf(b0.y) * h1;
        p0.z = __expf(b0.z) * h2;
        p0.w = __expf(b0.w) * h3;
        p1.x = __expf(b1.x) * h4;
        p1.y = __expf(b1.y) * h5;
        p1.z = __expf(b1.z) * h6;
        p1.w = __expf(b1.w) * h7;
        __builtin_nontemporal_store(p0, &lfw2[v]);
        __builtin_nontemporal_store(p1, &lfw2[v + 1]);
    }
}

extern "C" void kernel_launch(void* const* d_in, const int* in_sizes, int n_in,
                              void* d_out, int out_size, void* d_ws, size_t ws_size,
                              hipStream_t stream) {
    const float* w0 = (const float*)d_in[0];
    const float* w1 = (const float*)d_in[1];
    const float* w2 = (const float*)d_in[2];
    const int* r1 = (const int*)d_in[3];
    const int* r2 = (const int*)d_in[4];

    float* out = (float*)d_out;
    float* lfw0 = out;                        // [N_USERS]
    float* lfw1 = out + N_USERS;              // [N_EDGES]
    float* lfw2 = out + N_USERS + N_EDGES;    // [N_EDGES]

    // Scratch payload (100 MB) lives in the lfw1/lfw2 region (200 MB): it is
    // fully consumed by k_bucket before k_edges overwrites the region.
    uint32_t* payload = (uint32_t*)(out + N_USERS);

    float* ws = (float*)d_ws;
    __half* recip1 = (__half*)ws;                       // [N_USERS]  (2 MB)
    __half* recip2 = recip1 + N_USERS;                  // [N_ITEMS]  (0.4 MB)
    uint32_t* starts = (uint32_t*)(recip2 + N_ITEMS);   // [RUNS*(NB_U+1)] ~6 MB

    // Relation 1 (users)
    k_part<SHIFT_U, NB_U><<<NBLK, 1024, 0, stream>>>(w1, r1, payload, starts);
    k_bucket<SHIFT_U, NB_U><<<NB_U, 1024, 0, stream>>>(payload, starts,
                                                       N_USERS, w0, recip1, lfw0);

    // Relation 2 (items) — reuses payload/starts
    k_part<SHIFT_I, NB_I><<<NBLK, 1024, 0, stream>>>(w2, r2, payload, starts);
    k_bucket<SHIFT_I, NB_I><<<NB_I, 1024, 0, stream>>>(payload, starts,
                                                       N_ITEMS, nullptr, recip2, nullptr);

    // Per-edge finalize
    k_edges<<<2048, 256, 0, stream>>>((const f4*)w1, (const f4*)w2,
                                      (const i4*)r1, (const i4*)r2,
                                      recip1, recip2,
                                      (f4*)lfw1, (f4*)lfw2);
}

// Round 6
// 752.796 us; speedup vs baseline: 3.6517x; 1.0089x over previous
//
#include <hip/hip_runtime.h>
#include <hip/hip_fp16.h>
#include <stdint.h>

static constexpr int N_USERS = 1000000;
static constexpr int N_ITEMS = 200000;
static constexpr int N_EDGES = 25000000;

// Tile/partition geometry
static constexpr int TILE   = 16384;                 // edges per LDS-sorted tile
static constexpr int NTILES = 3;
static constexpr int CHUNK  = TILE * NTILES;         // 49152 edges per block
static constexpr int NBLK   = (N_EDGES + CHUNK - 1) / CHUNK;   // 509
static constexpr int RUNS   = NBLK * NTILES;         // runs per bucket = 1527

static constexpr int SHIFT_U = 10;                   // users: 1024 bins/bucket
static constexpr int SHIFT_I = 8;                    // items:  256 bins/bucket
static constexpr int NB_U = (N_USERS + (1 << SHIFT_U) - 1) >> SHIFT_U;  // 977
static constexpr int NB_I = (N_ITEMS + (1 << SHIFT_I) - 1) >> SHIFT_I;  // 782

typedef float    f4 __attribute__((ext_vector_type(4)));
typedef int      i4 __attribute__((ext_vector_type(4)));
typedef uint32_t u4 __attribute__((ext_vector_type(4)));

// ---------------------------------------------------------------------------
// P1: per-block tile-sorted partition. Restructured vs round 5:
//   pass 1 loads BOTH r and w, computes packed payload into REGISTERS
//   (exp overlaps the histogram LDS atomics); the scatter pass then runs
//   entirely from registers -> one exposed HBM round-trip per tile, and
//   w/r are read exactly once.
// ---------------------------------------------------------------------------
template<int SHIFT, int NB>
__global__ __launch_bounds__(1024) void k_part(const float* __restrict__ w,
                                               const int* __restrict__ r,
                                               uint32_t* __restrict__ payload,
                                               uint32_t* __restrict__ starts) {
    __shared__ uint32_t stage[TILE];     // 64 KB
    __shared__ uint32_t hist[1024];      // histogram, then write cursors
    __shared__ uint32_t wsum[16];
    const int blk = blockIdx.x;
    const int t = threadIdx.x;
    const int lane = t & 63, wave = t >> 6;
    const int begin = blk * CHUNK;
    const int bend = (begin + CHUNK < N_EDGES) ? begin + CHUNK : N_EDGES;
    const uint32_t lmask = (1u << SHIFT) - 1u;

    for (int tile = 0; tile < NTILES; ++tile) {
        const int tb = begin + tile * TILE;
        int n = bend - tb;
        n = n < 0 ? 0 : (n > TILE ? TILE : n);
        const int n4 = n >> 2;                       // all boundaries %4 == 0
        const size_t mbase = (size_t)(blk * NTILES + tile) * (NB + 1);

        hist[t] = 0;
        __syncthreads();

        // 1) load r+w, build payload in regs, histogram
        uint32_t idx[16];
        uint32_t pay[16];
        #pragma unroll
        for (int k = 0; k < 4; ++k) {
            int v = t + k * 1024;
            if (v < n4) {
                i4 u = __builtin_nontemporal_load((const i4*)r + (tb >> 2) + v);
                f4 a = __builtin_nontemporal_load((const f4*)w + (tb >> 2) + v);
                idx[4 * k + 0] = (uint32_t)u.x;
                idx[4 * k + 1] = (uint32_t)u.y;
                idx[4 * k + 2] = (uint32_t)u.z;
                idx[4 * k + 3] = (uint32_t)u.w;
                pay[4 * k + 0] = (__float_as_uint(__expf(a.x)) & ~lmask) | ((uint32_t)u.x & lmask);
                pay[4 * k + 1] = (__float_as_uint(__expf(a.y)) & ~lmask) | ((uint32_t)u.y & lmask);
                pay[4 * k + 2] = (__float_as_uint(__expf(a.z)) & ~lmask) | ((uint32_t)u.z & lmask);
                pay[4 * k + 3] = (__float_as_uint(__expf(a.w)) & ~lmask) | ((uint32_t)u.w & lmask);
                atomicAdd(&hist[(uint32_t)u.x >> SHIFT], 1u);
                atomicAdd(&hist[(uint32_t)u.y >> SHIFT], 1u);
                atomicAdd(&hist[(uint32_t)u.z >> SHIFT], 1u);
                atomicAdd(&hist[(uint32_t)u.w >> SHIFT], 1u);
            }
        }
        __syncthreads();

        // 2) exclusive scan of hist[0..1023]: wave shfl-scan + wave-total scan
        uint32_t c = hist[t];
        uint32_t x = c;
        #pragma unroll
        for (int d = 1; d < 64; d <<= 1) {
            uint32_t y = __shfl_up(x, d);
            if (lane >= d) x += y;
        }
        if (lane == 63) wsum[wave] = x;
        __syncthreads();
        if (t < 16) {
            uint32_t y = wsum[t];
            uint32_t s = y;
            #pragma unroll
            for (int d = 1; d < 16; d <<= 1) {
                uint32_t z = __shfl_up(s, d, 16);
                if (t >= d) s += z;
            }
            wsum[t] = s - y;                         // exclusive wave prefix
        }
        __syncthreads();
        uint32_t excl = x - c + wsum[wave];

        if (t < NB) starts[mbase + t] = (uint32_t)tb + excl;
        if (t == 0) starts[mbase + NB] = (uint32_t)(tb + n);  // sentinel
        hist[t] = excl;                              // tile-local cursors
        __syncthreads();

        // 3) scatter into LDS stage (registers only, no memory re-read)
        #pragma unroll
        for (int k = 0; k < 4; ++k) {
            int v = t + k * 1024;
            if (v < n4) {
                uint32_t p0 = atomicAdd(&hist[idx[4 * k + 0] >> SHIFT], 1u);
                stage[p0] = pay[4 * k + 0];
                uint32_t p1 = atomicAdd(&hist[idx[4 * k + 1] >> SHIFT], 1u);
                stage[p1] = pay[4 * k + 1];
                uint32_t p2 = atomicAdd(&hist[idx[4 * k + 2] >> SHIFT], 1u);
                stage[p2] = pay[4 * k + 2];
                uint32_t p3 = atomicAdd(&hist[idx[4 * k + 3] >> SHIFT], 1u);
                stage[p3] = pay[4 * k + 3];
            }
        }
        __syncthreads();

        // 4) coalesced dump of the sorted tile
        #pragma unroll
        for (int k = 0; k < 4; ++k) {
            int v = t + k * 1024;
            if (v < n4) {
                u4 s4 = ((const u4*)stage)[v];
                __builtin_nontemporal_store(s4, (u4*)payload + (tb >> 2) + v);
            }
        }
        __syncthreads();                             // before next tile's hist[]=0
    }
}

// ---------------------------------------------------------------------------
// P2: one block per bucket. 8 lanes per run (8 runs per wave) instead of a
// whole wave per ~17-entry run -> ~3x lane efficiency. Emits f16 reciprocals
// (L2-resident gather table); users variant fuses exp(w0) self term + lfw0.
// ---------------------------------------------------------------------------
template<int SHIFT, int NB>
__global__ __launch_bounds__(1024) void k_bucket(const uint32_t* __restrict__ payload,
                                                 const uint32_t* __restrict__ starts,
                                                 int nelems,
                                                 const float* __restrict__ w0,   // null for items
                                                 __half* __restrict__ recip,
                                                 float* __restrict__ lfw0) {     // null for items
    constexpr int BINS = 1 << SHIFT;
    __shared__ float bins[BINS];
    const int b = blockIdx.x;
    const int t = threadIdx.x;
    const uint32_t lmask = (1u << SHIFT) - 1u;
    for (int i = t; i < BINS; i += 1024) bins[i] = 0.f;
    __syncthreads();

    const int wave = t >> 6, lane = t & 63;          // 16 waves
    const int sub = lane >> 3;                       // 8 sub-groups / wave
    const int sl = lane & 7;                         // lane within sub-group
    for (int run = wave * 8 + sub; run < RUNS; run += 128) {
        uint32_t s = __builtin_nontemporal_load(&starts[(size_t)run * (NB + 1) + b]);
        uint32_t e = __builtin_nontemporal_load(&starts[(size_t)run * (NB + 1) + b + 1]);
        for (uint32_t j = s + sl; j < e; j += 8) {
            uint32_t p = __builtin_nontemporal_load(&payload[j]);
            atomicAdd(&bins[p & lmask], __uint_as_float(p & ~lmask));
        }
    }
    __syncthreads();

    for (int i = t; i < BINS; i += 1024) {
        int g = b * BINS + i;
        if (g < nelems) {
            float s = bins[i];
            if (w0) {
                float e = __expf(w0[g]);
                s += e;
                lfw0[g] = e / s;
            }
            recip[g] = __float2half(1.0f / s);
        }
    }
}

// ---------------------------------------------------------------------------
// Per-edge finalize for ONE relation, unrolled x4: 16 independent gathers
// in flight per thread at <=64 VGPR (8 waves/SIMD).
//   out = exp(w) * recip[r]
// ---------------------------------------------------------------------------
__global__ __launch_bounds__(256) void k_edge(const f4* __restrict__ w,
                                              const i4* __restrict__ r,
                                              const __half* __restrict__ recip,
                                              f4* __restrict__ out) {
    const int nq = N_EDGES / 16;                     // 1,562,500 (exact)
    int tid = blockIdx.x * blockDim.x + threadIdx.x;
    int stride = gridDim.x * blockDim.x;
    for (int q = tid; q < nq; q += stride) {
        int v = q * 4;
        i4 u0 = __builtin_nontemporal_load(&r[v + 0]);
        i4 u1 = __builtin_nontemporal_load(&r[v + 1]);
        i4 u2 = __builtin_nontemporal_load(&r[v + 2]);
        i4 u3 = __builtin_nontemporal_load(&r[v + 3]);
        float g0  = __half2float(recip[u0.x]);
        float g1  = __half2float(recip[u0.y]);
        float g2  = __half2float(recip[u0.z]);
        float g3  = __half2float(recip[u0.w]);
        float g4  = __half2float(recip[u1.x]);
        float g5  = __half2float(recip[u1.y]);
        float g6  = __half2float(recip[u1.z]);
        float g7  = __half2float(recip[u1.w]);
        float g8  = __half2float(recip[u2.x]);
        float g9  = __half2float(recip[u2.y]);
        float g10 = __half2float(recip[u2.z]);
        float g11 = __half2float(recip[u2.w]);
        float g12 = __half2float(recip[u3.x]);
        float g13 = __half2float(recip[u3.y]);
        float g14 = __half2float(recip[u3.z]);
        float g15 = __half2float(recip[u3.w]);
        f4 a0 = __builtin_nontemporal_load(&w[v + 0]);
        f4 a1 = __builtin_nontemporal_load(&w[v + 1]);
        f4 a2 = __builtin_nontemporal_load(&w[v + 2]);
        f4 a3 = __builtin_nontemporal_load(&w[v + 3]);
        f4 o;
        o.x = __expf(a0.x) * g0;
        o.y = __expf(a0.y) * g1;
        o.z = __expf(a0.z) * g2;
        o.w = __expf(a0.w) * g3;
        __builtin_nontemporal_store(o, &out[v + 0]);
        o.x = __expf(a1.x) * g4;
        o.y = __expf(a1.y) * g5;
        o.z = __expf(a1.z) * g6;
        o.w = __expf(a1.w) * g7;
        __builtin_nontemporal_store(o, &out[v + 1]);
        o.x = __expf(a2.x) * g8;
        o.y = __expf(a2.y) * g9;
        o.z = __expf(a2.z) * g10;
        o.w = __expf(a2.w) * g11;
        __builtin_nontemporal_store(o, &out[v + 2]);
        o.x = __expf(a3.x) * g12;
        o.y = __expf(a3.y) * g13;
        o.z = __expf(a3.z) * g14;
        o.w = __expf(a3.w) * g15;
        __builtin_nontemporal_store(o, &out[v + 3]);
    }
}

extern "C" void kernel_launch(void* const* d_in, const int* in_sizes, int n_in,
                              void* d_out, int out_size, void* d_ws, size_t ws_size,
                              hipStream_t stream) {
    const float* w0 = (const float*)d_in[0];
    const float* w1 = (const float*)d_in[1];
    const float* w2 = (const float*)d_in[2];
    const int* r1 = (const int*)d_in[3];
    const int* r2 = (const int*)d_in[4];

    float* out = (float*)d_out;
    float* lfw0 = out;                        // [N_USERS]
    float* lfw1 = out + N_USERS;              // [N_EDGES]
    float* lfw2 = out + N_USERS + N_EDGES;    // [N_EDGES]

    // Scratch payload (100 MB) lives in the lfw1/lfw2 region (200 MB): it is
    // fully consumed by k_bucket before the k_edge kernels overwrite it.
    uint32_t* payload = (uint32_t*)(out + N_USERS);

    float* ws = (float*)d_ws;
    __half* recip1 = (__half*)ws;                       // [N_USERS]  (2 MB)
    __half* recip2 = recip1 + N_USERS;                  // [N_ITEMS]  (0.4 MB)
    uint32_t* starts = (uint32_t*)(recip2 + N_ITEMS);   // [RUNS*(NB_U+1)] ~6 MB

    // Relation 1 (users)
    k_part<SHIFT_U, NB_U><<<NBLK, 1024, 0, stream>>>(w1, r1, payload, starts);
    k_bucket<SHIFT_U, NB_U><<<NB_U, 1024, 0, stream>>>(payload, starts,
                                                       N_USERS, w0, recip1, lfw0);

    // Relation 2 (items) — reuses payload/starts
    k_part<SHIFT_I, NB_I><<<NBLK, 1024, 0, stream>>>(w2, r2, payload, starts);
    k_bucket<SHIFT_I, NB_I><<<NB_I, 1024, 0, stream>>>(payload, starts,
                                                       N_ITEMS, nullptr, recip2, nullptr);

    // Per-edge finalize (payload fully consumed; safe to overwrite lfw1)
    k_edge<<<2048, 256, 0, stream>>>((const f4*)w1, (const i4*)r1, recip1, (f4*)lfw1);
    k_edge<<<2048, 256, 0, stream>>>((const f4*)w2, (const i4*)r2, recip2, (f4*)lfw2);
}